// Round 5
// baseline (433.536 us; speedup 1.0000x reference)
//
#include <hip/hip_runtime.h>
#include <stdint.h>

// T,B,I,H,K = 200,2048,128,128,4
#define T_DIM 200
#define B_DIM 2048
#define I_DIM 128
#define H_DIM 128
#define TS    16
#define NC    13    // ceil(T/TS)

typedef float  f32x4  __attribute__((ext_vector_type(4)));
typedef __bf16 bf16x8 __attribute__((ext_vector_type(8)));

union BF8 { ushort4 u2[2]; bf16x8 v; };

static __device__ __forceinline__ unsigned short f2bf(float f) {
    union { float f; unsigned u; } c; c.f = f;
    unsigned u = c.u + (0x7FFFu + ((c.u >> 16) & 1u));   // RNE
    return (unsigned short)(u >> 16);
}
static __device__ __forceinline__ bf16x8 cvt8(const float4 a, const float4 b) {
    BF8 t;
    t.u2[0] = make_ushort4(f2bf(a.x), f2bf(a.y), f2bf(a.z), f2bf(a.w));
    t.u2[1] = make_ushort4(f2bf(b.x), f2bf(b.y), f2bf(b.z), f2bf(b.w));
    return t.v;
}

// ---------------------------------------------------------------------------
// K0: w1 fp32 -> bf16 (row-major, same layout). 16 blocks x 256 thr x 4 elems.
// ---------------------------------------------------------------------------
__global__ __launch_bounds__(256) void k0_cvt(
    const float* __restrict__ w1, unsigned short* __restrict__ w1b)
{
    const int idx = (blockIdx.x * 256 + threadIdx.x) * 4;
    const float4 v = *(const float4*)(w1 + idx);
    *(ushort4*)(w1b + idx) = make_ushort4(f2bf(v.x), f2bf(v.y), f2bf(v.z), f2bf(v.w));
}

// ---------------------------------------------------------------------------
// K1: chunk column sums. Block (c,b): part[b][c][i] = sum_{t in chunk, t<start}
// x[t][b][i]. Uniform work; blocks with 16c >= start exit immediately.
// ---------------------------------------------------------------------------
__global__ __launch_bounds__(256) void k1_sums(
    const float* __restrict__ x, const int* __restrict__ lengths,
    float* __restrict__ part)
{
    const int c = blockIdx.x, b = blockIdx.y;
    const int L = lengths[b];
    const int start = (L > 4) ? (L - 4) : 0;
    const int t0 = c * TS;
    if (t0 >= start) return;

    __shared__ float red[128];
    const int i = threadIdx.x & 127;
    const int g = threadIdx.x >> 7;
    const float* xp = x + (size_t)b * I_DIM + i;
    float s = 0.f;
    #pragma unroll
    for (int r = 0; r < 8; ++r) {
        const int t = t0 + g * 8 + r;        // uniform condition -> cheap skip
        if (t < start) s += xp[(size_t)t * (B_DIM * I_DIM)];
    }
    if (g == 1) red[i] = s;
    __syncthreads();
    if (g == 0) part[((size_t)b * NC + c) * I_DIM + i] = s + red[i];
}

// ---------------------------------------------------------------------------
// K2: per b. Combine chunk partials -> prefix at labeled steps; mini-GEMM
// {x_lab, m_s}@{w2,w3}^T (16x16x32 MFMA, rows duplicated l15&3);
// writes ektw[b][h][k] = exp(-(x2l+wms)) and out init = masked x2_lab.
// ---------------------------------------------------------------------------
__global__ __launch_bounds__(256) void k2_label(
    const float* __restrict__ x, const int* __restrict__ lengths,
    const float* __restrict__ w2, const float* __restrict__ w3,
    const float* __restrict__ part, float* __restrict__ ektw,
    float* __restrict__ out)
{
    __shared__ __align__(16) unsigned short axl[4][136];
    __shared__ __align__(16) unsigned short ams[4][136];

    const int b   = blockIdx.x;
    const int tid = threadIdx.x;
    const int L     = lengths[b];
    const int start = (L > 4) ? (L - 4) : 0;
    const int nv    = (L < 4) ? L : 4;

    if (tid < 128) {
        const int i = tid;
        float p = 0.f;
        const int ncs = (start + TS - 1) / TS;     // chunks with 16c < start
        for (int cc = 0; cc < ncs; ++cc)
            p += part[((size_t)b * NC + cc) * I_DIM + i];
        const float* xi = x + (size_t)b * I_DIM + i;
        const float v0 = xi[(size_t)(start + 0) * (B_DIM * I_DIM)];
        const float v1 = xi[(size_t)(start + 1) * (B_DIM * I_DIM)];
        const float v2 = xi[(size_t)(start + 2) * (B_DIM * I_DIM)];
        const float v3 = xi[(size_t)(start + 3) * (B_DIM * I_DIM)];
        const float p0 = p + v0, p1 = p0 + v1, p2 = p1 + v2, p3 = p2 + v3;
        axl[0][i] = f2bf(v0); axl[1][i] = f2bf(v1);
        axl[2][i] = f2bf(v2); axl[3][i] = f2bf(v3);
        ams[0][i] = f2bf(p0 / (float)(start + 1));
        ams[1][i] = f2bf(p1 / (float)(start + 2));
        ams[2][i] = f2bf(p2 / (float)(start + 3));
        ams[3][i] = f2bf(p3 / (float)(start + 4));
    }
    __syncthreads();

    const int lane = tid & 63, wv = tid >> 6, l15 = lane & 15, quad = lane >> 4;
    #pragma unroll
    for (int nt = 0; nt < 2; ++nt) {
        const int n = wv * 32 + nt * 16 + l15;      // output h
        f32x4 c1 = (f32x4){0.f, 0.f, 0.f, 0.f};
        f32x4 c2 = (f32x4){0.f, 0.f, 0.f, 0.f};
        #pragma unroll
        for (int ks = 0; ks < 4; ++ks) {
            const int kc = ks * 32 + quad * 8;
            const bf16x8 a1 = *(const bf16x8*)&axl[l15 & 3][kc];
            const bf16x8 a2 = *(const bf16x8*)&ams[l15 & 3][kc];
            const bf16x8 b2 = cvt8(*(const float4*)(w2 + (size_t)n * I_DIM + kc),
                                   *(const float4*)(w2 + (size_t)n * I_DIM + kc + 4));
            const bf16x8 b3 = cvt8(*(const float4*)(w3 + (size_t)n * I_DIM + kc),
                                   *(const float4*)(w3 + (size_t)n * I_DIM + kc + 4));
            c1 = __builtin_amdgcn_mfma_f32_16x16x32_bf16(a1, b2, c1, 0, 0, 0);
            c2 = __builtin_amdgcn_mfma_f32_16x16x32_bf16(a2, b3, c2, 0, 0, 0);
        }
        if (quad == 0) {        // D rows 0..3 = k
            f32x4 e;
            #pragma unroll
            for (int r = 0; r < 4; ++r) {
                e[r] = __builtin_amdgcn_exp2f(-1.44269504f * (c1[r] + c2[r]));
                out[((size_t)b * 4 + r) * H_DIM + n] = (r < nv) ? c1[r] : 0.f;
            }
            *(f32x4*)(ektw + ((size_t)b * H_DIM + n) * 4) = e;
        }
    }
}

// ---------------------------------------------------------------------------
// K3: one 16-s tile per block (c,b). Transposed MFMA (A=w1, B=x -> D[h][s]):
// lane = (s=l15, h=quad*4+r+16nt+32wv). E-phase h-accum is in-lane; att
// reduce = 2 shfl + LDS wave-combine; ACC in-lane; s-reduce 4 shfl; atomic out.
// ---------------------------------------------------------------------------
__global__ __launch_bounds__(256) void k3_tile(
    const float* __restrict__ x, const int* __restrict__ lengths,
    const unsigned short* __restrict__ w1b, const float* __restrict__ b1,
    const float* __restrict__ w0, const float* __restrict__ ektw,
    float* __restrict__ out)
{
    const int c = blockIdx.x, b = blockIdx.y;
    const int L  = lengths[b];
    const int t0 = c * TS;
    if (t0 >= L) return;
    const int start = (L > 4) ? (L - 4) : 0;
    const int nv    = (L < 4) ? L : 4;

    __shared__ __align__(16) unsigned short xs[TS][136];   // 4352 B
    __shared__ __align__(16) float ektLS[H_DIM][4];        // 2048 B
    __shared__ __align__(16) float attp[4][TS][4];         // 1024 B

    const int tid  = threadIdx.x;
    const int lane = tid & 63;
    const int wv   = tid >> 6;
    const int l15  = lane & 15;
    const int quad = lane >> 4;
    const int hb   = wv * 32;

    // stage x tile -> bf16 LDS (one conversion per block), zero-fill t>=L
    {
        const int r = tid >> 4, seg = tid & 15;
        const int t = t0 + r;
        ushort4 wa = make_ushort4(0, 0, 0, 0), wb = make_ushort4(0, 0, 0, 0);
        if (t < L) {
            const float* xr = x + ((size_t)t * B_DIM + b) * I_DIM + seg * 8;
            const float4 p0 = *(const float4*)(xr);
            const float4 p1 = *(const float4*)(xr + 4);
            wa = make_ushort4(f2bf(p0.x), f2bf(p0.y), f2bf(p0.z), f2bf(p0.w));
            wb = make_ushort4(f2bf(p1.x), f2bf(p1.y), f2bf(p1.z), f2bf(p1.w));
        }
        *(ushort4*)&xs[r][seg * 8]     = wa;
        *(ushort4*)&xs[r][seg * 8 + 4] = wb;
    }
    // stage ekt for this b
    if (tid < 128)
        *(f32x4*)&ektLS[tid][0] = *(const f32x4*)(ektw + ((size_t)b * H_DIM + tid) * 4);
    __syncthreads();

    // A-frags (w1 bf16, straight loads) + B-frags (x tile from LDS)
    bf16x8 afr[2][4];
    #pragma unroll
    for (int nt = 0; nt < 2; ++nt)
        #pragma unroll
        for (int ks = 0; ks < 4; ++ks)
            afr[nt][ks] = *(const bf16x8*)(
                w1b + (size_t)(hb + nt * 16 + l15) * I_DIM + ks * 32 + quad * 8);
    bf16x8 xfr[4];
    #pragma unroll
    for (int ks = 0; ks < 4; ++ks)
        xfr[ks] = *(const bf16x8*)&xs[l15][ks * 32 + quad * 8];

    // MFMA: D[h][s]; lane holds s=l15, h=hb+nt*16+quad*4+r
    float  x1c[2][4];
    float4 bias4[2], w04[2];
    #pragma unroll
    for (int nt = 0; nt < 2; ++nt) {
        f32x4 acc = (f32x4){0.f, 0.f, 0.f, 0.f};
        #pragma unroll
        for (int ks = 0; ks < 4; ++ks)
            acc = __builtin_amdgcn_mfma_f32_16x16x32_bf16(afr[nt][ks], xfr[ks], acc, 0, 0, 0);
        bias4[nt] = *(const float4*)(b1 + hb + nt * 16 + quad * 4);
        w04[nt]   = *(const float4*)(w0 + hb + nt * 16 + quad * 4);
        const float* bp = (const float*)&bias4[nt];
        #pragma unroll
        for (int r = 0; r < 4; ++r) x1c[nt][r] = acc[r] + bp[r];
    }

    // E phase: in-lane accumulation over this lane's 8 h values
    float att[4] = {0.f, 0.f, 0.f, 0.f};
    #pragma unroll
    for (int nt = 0; nt < 2; ++nt) {
        const float* wp = (const float*)&w04[nt];
        #pragma unroll
        for (int r = 0; r < 4; ++r) {
            const f32x4 ekv = *(const f32x4*)&ektLS[hb + nt * 16 + quad * 4 + r][0];
            const float E  = __builtin_amdgcn_exp2f(-1.44269504f * x1c[nt][r]);
            const float wh = wp[r];
            #pragma unroll
            for (int k = 0; k < 4; ++k)
                att[k] += wh * __builtin_amdgcn_rcpf(1.f + E * ekv[k]);
        }
    }
    // reduce over quads (h direction): 2 shfl steps
    #pragma unroll
    for (int k = 0; k < 4; ++k) {
        att[k] += __shfl_xor(att[k], 16);
        att[k] += __shfl_xor(att[k], 32);
    }
    if (quad == 0)
        *(f32x4*)&attp[wv][l15][0] = (f32x4){att[0], att[1], att[2], att[3]};
    __syncthreads();

    // combine 4 waves + mask; s = t0 + l15
    f32x4 as = *(const f32x4*)&attp[0][l15][0];
    as += *(const f32x4*)&attp[1][l15][0];
    as += *(const f32x4*)&attp[2][l15][0];
    as += *(const f32x4*)&attp[3][l15][0];
    const int s = t0 + l15;
    float am[4];
    #pragma unroll
    for (int k = 0; k < 4; ++k)
        am[k] = (k < nv && s <= start + k) ? as[k] : 0.f;

    // ACC (in-lane) + s-reduce (4 shfl) + atomic add into out
    #pragma unroll
    for (int nt = 0; nt < 2; ++nt) {
        #pragma unroll
        for (int r = 0; r < 4; ++r) {
            float v0 = am[0] * x1c[nt][r];
            float v1 = am[1] * x1c[nt][r];
            float v2 = am[2] * x1c[nt][r];
            float v3 = am[3] * x1c[nt][r];
            #pragma unroll
            for (int m = 1; m <= 8; m <<= 1) {
                v0 += __shfl_xor(v0, m);
                v1 += __shfl_xor(v1, m);
                v2 += __shfl_xor(v2, m);
                v3 += __shfl_xor(v3, m);
            }
            if (l15 == 0) {
                const int h = hb + nt * 16 + quad * 4 + r;
                atomicAdd(&out[((size_t)b * 4 + 0) * H_DIM + h], v0);
                atomicAdd(&out[((size_t)b * 4 + 1) * H_DIM + h], v1);
                atomicAdd(&out[((size_t)b * 4 + 2) * H_DIM + h], v2);
                atomicAdd(&out[((size_t)b * 4 + 3) * H_DIM + h], v3);
            }
        }
    }
}

// ---------------------------------------------------------------------------
extern "C" void kernel_launch(void* const* d_in, const int* in_sizes, int n_in,
                              void* d_out, int out_size, void* d_ws, size_t ws_size,
                              hipStream_t stream) {
    (void)in_sizes; (void)n_in; (void)out_size; (void)ws_size;
    const float* x       = (const float*)d_in[0];
    const int*   lengths = (const int*)d_in[1];
    // d_in[2] = label_len (==4, hard-coded)
    const float* w0 = (const float*)d_in[3];
    const float* w1 = (const float*)d_in[4];
    const float* b1 = (const float*)d_in[5];
    const float* w2 = (const float*)d_in[6];
    const float* w3 = (const float*)d_in[7];
    float* out = (float*)d_out;

    // ws carve-up: w1bf 32 KB | part 13.6 MB | ektw 4 MB  (~17.7 MB total)
    unsigned short* w1bf = (unsigned short*)d_ws;
    float* part = (float*)((char*)d_ws + 32768);
    float* ektw = (float*)((char*)d_ws + 32768 + (size_t)B_DIM * NC * I_DIM * 4);

    k0_cvt <<<dim3(16),         256, 0, stream>>>(w1, w1bf);
    k1_sums<<<dim3(NC, B_DIM),  256, 0, stream>>>(x, lengths, part);
    k2_label<<<dim3(B_DIM),     256, 0, stream>>>(x, lengths, w2, w3, part, ektw, out);
    k3_tile<<<dim3(NC, B_DIM),  256, 0, stream>>>(x, lengths, w1bf, b1, w0, ektw, out);
}